// Round 5
// baseline (386.530 us; speedup 1.0000x reference)
//
#include <hip/hip_runtime.h>
#include <hip/hip_bf16.h>
#include <math.h>

// Problem constants
#define S 2048
#define HID 2048
#define NH 16
#define KVH 8
#define HD 128
#define EPS 1e-6f
#define QK_SCALE 11.313708498984760390f  // 1/SCALING = sqrt(128)

typedef __attribute__((ext_vector_type(8))) short s16x8;
typedef __attribute__((ext_vector_type(4))) float f32x4;

__device__ __forceinline__ unsigned short f2bf(float f) {
  __hip_bfloat16 h = __float2bfloat16(f);
  return *(unsigned short*)&h;
}
__device__ __forceinline__ float bf2f(unsigned short u) {
  unsigned int x = ((unsigned int)u) << 16;
  return __builtin_bit_cast(float, x);
}

__device__ __forceinline__ void gload16(const void* g, void* l) {
  __builtin_amdgcn_global_load_lds(
      (const __attribute__((address_space(1))) void*)g,
      (__attribute__((address_space(3))) void*)l, 16, 0, 0);
}

// ---------------------------------------------------------------------------
// fp32 -> split bf16 (hi + lo) elementwise.
// ---------------------------------------------------------------------------
__global__ __launch_bounds__(256) void f32_to_bf16_split(const float* __restrict__ in,
                                                         unsigned short* __restrict__ hi,
                                                         unsigned short* __restrict__ lo,
                                                         int n4) {
  const int i = blockIdx.x * 256 + threadIdx.x;
  if (i < n4) {
    const float4 v = *(const float4*)(in + (size_t)i * 4);
    ushort4 h, l;
    h.x = f2bf(v.x); l.x = f2bf(v.x - bf2f(h.x));
    h.y = f2bf(v.y); l.y = f2bf(v.y - bf2f(h.y));
    h.z = f2bf(v.z); l.z = f2bf(v.z - bf2f(h.z));
    h.w = f2bf(v.w); l.w = f2bf(v.w - bf2f(h.w));
    *(ushort4*)(hi + (size_t)i * 4) = h;
    *(ushort4*)(lo + (size_t)i * 4) = l;
  }
}

// ---------------------------------------------------------------------------
// Transpose fp32 [K][N] -> bf16 [N][K], plain.
// ---------------------------------------------------------------------------
__global__ __launch_bounds__(256) void transpose_to_bf16(const float* __restrict__ in,
                                                         unsigned short* __restrict__ out,
                                                         int K, int N) {
  __shared__ float t[64][65];
  const int n0 = blockIdx.x * 64;
  const int k0 = blockIdx.y * 64;
  const int tid = threadIdx.x;

  for (int idx = tid; idx < 64 * 16; idx += 256) {
    const int r = idx >> 4;
    const int c4 = (idx & 15) * 4;
    const float4 v = *(const float4*)(in + (size_t)(k0 + r) * N + n0 + c4);
    t[r][c4 + 0] = v.x; t[r][c4 + 1] = v.y; t[r][c4 + 2] = v.z; t[r][c4 + 3] = v.w;
  }
  __syncthreads();
  for (int idx = tid; idx < 64 * 16; idx += 256) {
    const int a = idx >> 4;
    const int b4 = (idx & 15) * 4;
    ushort4 u;
    u.x = f2bf(t[b4 + 0][a]); u.y = f2bf(t[b4 + 1][a]);
    u.z = f2bf(t[b4 + 2][a]); u.w = f2bf(t[b4 + 3][a]);
    *(ushort4*)(out + (size_t)(n0 + a) * K + k0 + b4) = u;
  }
}

// ---------------------------------------------------------------------------
// Transpose fp32 [K][N] -> split bf16 hi/lo [N][K].
// ---------------------------------------------------------------------------
__global__ __launch_bounds__(256) void transpose_to_bf16_split(const float* __restrict__ in,
                                                               unsigned short* __restrict__ ohi,
                                                               unsigned short* __restrict__ olo,
                                                               int K, int N) {
  __shared__ float t[64][65];
  const int n0 = blockIdx.x * 64;
  const int k0 = blockIdx.y * 64;
  const int tid = threadIdx.x;

  for (int idx = tid; idx < 64 * 16; idx += 256) {
    const int r = idx >> 4;
    const int c4 = (idx & 15) * 4;
    const float4 v = *(const float4*)(in + (size_t)(k0 + r) * N + n0 + c4);
    t[r][c4 + 0] = v.x; t[r][c4 + 1] = v.y; t[r][c4 + 2] = v.z; t[r][c4 + 3] = v.w;
  }
  __syncthreads();
  for (int idx = tid; idx < 64 * 16; idx += 256) {
    const int a = idx >> 4;
    const int b4 = (idx & 15) * 4;
    ushort4 h, l;
#pragma unroll
    for (int q = 0; q < 4; ++q) {
      const float v = t[b4 + q][a];
      const unsigned short hu = f2bf(v);
      const unsigned short lu = f2bf(v - bf2f(hu));
      ((unsigned short*)&h)[q] = hu;
      ((unsigned short*)&l)[q] = lu;
    }
    *(ushort4*)(ohi + (size_t)(n0 + a) * K + k0 + b4) = h;
    *(ushort4*)(olo + (size_t)(n0 + a) * K + k0 + b4) = l;
  }
}

#define BK 32

// ---------------------------------------------------------------------------
// FUSED QK projection: 64x128-tile split-precision GEMM + RMSNorm + RoPE +
// split-bf16 store. One block column == one head (128 dims), so the rmsnorm
// reduction is block-local. Grid (24 heads, 32 m-tiles) = 768 = 3/CU even.
// Eliminates the 24MB fp32 qk_buf round-trip and the standalone rmsnorm
// kernel (48MB HBM + 12288-block launch saved).
// Epilogue math is operation-identical to the old rmsnorm_rope_split kernel
// (same reduction order) -> bitwise-identical q/k, absmax must not move.
// ---------------------------------------------------------------------------
__global__ __launch_bounds__(256) void gemm_qk_fused(const unsigned short* __restrict__ Ahi,
                                                     const unsigned short* __restrict__ Alo,
                                                     const unsigned short* __restrict__ Bhi,
                                                     const unsigned short* __restrict__ Blo,
                                                     const float* __restrict__ cosb,
                                                     const float* __restrict__ sinb,
                                                     unsigned short* __restrict__ qh,
                                                     unsigned short* __restrict__ ql,
                                                     unsigned short* __restrict__ kh,
                                                     unsigned short* __restrict__ kl) {
  __shared__ char smem[64 * 132 * 4];  // 33792 B; staging uses first 24KB
  unsigned short* AsH = (unsigned short*)smem;            // 64x32 = 4KB
  unsigned short* AsL = (unsigned short*)(smem + 4096);
  unsigned short* BsH = (unsigned short*)(smem + 8192);   // 128x32 = 8KB
  unsigned short* BsL = (unsigned short*)(smem + 16384);
  float* Sf = (float*)smem;  // [64][132] fp32 after the GEMM (pad: no bank conflict)

  const int tid = threadIdx.x;
  const int lane = tid & 63;
  const int wave = tid >> 6;
  const int hh = blockIdx.x;          // head 0..23 (q:0-15, k:16-23)
  const int m0 = blockIdx.y * 64;
  const int n0 = hh * 128;

  const int qm = (wave >> 1) * 32;
  const int qn = (wave & 1) * 64;
  const int l15 = lane & 15;
  const int quad = lane >> 4;
  const int st_row = lane >> 2;
  const int st_col = (lane & 3) * 8;

  f32x4 acc[2][4] = {};

  for (int k0 = 0; k0 < HID; k0 += BK) {
    {
      const int rb = wave * 16;
      const size_t aoff = (size_t)(m0 + rb + st_row) * HID + k0 + st_col;
      gload16(Ahi + aoff, &AsH[rb * BK]);
      gload16(Alo + aoff, &AsL[rb * BK]);
    }
#pragma unroll
    for (int p = 0; p < 2; ++p) {
      const int rb = p * 64 + wave * 16;
      const size_t boff = (size_t)(n0 + rb + st_row) * HID + k0 + st_col;
      gload16(Bhi + boff, &BsH[rb * BK]);
      gload16(Blo + boff, &BsL[rb * BK]);
    }
    __syncthreads();

    s16x8 ah[2], al[2], bh[4], bl[4];
#pragma unroll
    for (int i = 0; i < 2; ++i) {
      const int ro = (qm + i * 16 + l15) * BK + quad * 8;
      ah[i] = *(const s16x8*)&AsH[ro];
      al[i] = *(const s16x8*)&AsL[ro];
    }
#pragma unroll
    for (int j = 0; j < 4; ++j) {
      const int ro = (qn + j * 16 + l15) * BK + quad * 8;
      bh[j] = *(const s16x8*)&BsH[ro];
      bl[j] = *(const s16x8*)&BsL[ro];
    }
#pragma unroll
    for (int i = 0; i < 2; ++i)
#pragma unroll
      for (int j = 0; j < 4; ++j) {
        acc[i][j] = __builtin_amdgcn_mfma_f32_16x16x32_bf16(ah[i], bh[j], acc[i][j], 0, 0, 0);
        acc[i][j] = __builtin_amdgcn_mfma_f32_16x16x32_bf16(ah[i], bl[j], acc[i][j], 0, 0, 0);
        acc[i][j] = __builtin_amdgcn_mfma_f32_16x16x32_bf16(al[i], bh[j], acc[i][j], 0, 0, 0);
      }
    __syncthreads();
  }

  // ---- epilogue: S -> LDS (fp32, padded row stride 132) ----
#pragma unroll
  for (int i = 0; i < 2; ++i) {
    const int rbase = qm + i * 16 + quad * 4;
#pragma unroll
    for (int j = 0; j < 4; ++j) {
      const int col = qn + j * 16 + l15;
#pragma unroll
      for (int r = 0; r < 4; ++r)
        Sf[(rbase + r) * 132 + col] = acc[i][j][r];
    }
  }
  __syncthreads();

  // ---- fused RMSNorm + RoPE + split store; wave owns rows wave*16..+15 ----
  const bool is_q = (hh < 16);
  for (int rr = 0; rr < 16; ++rr) {
    const int row = wave * 16 + rr;
    const int s = m0 + row;
    const float x1 = Sf[row * 132 + lane];
    const float x2 = Sf[row * 132 + 64 + lane];

    float ss = x1 * x1 + x2 * x2;
    ss += __shfl_xor(ss, 1);
    ss += __shfl_xor(ss, 2);
    ss += __shfl_xor(ss, 4);
    ss += __shfl_xor(ss, 8);
    ss += __shfl_xor(ss, 16);
    ss += __shfl_xor(ss, 32);
    const float rn = rsqrtf(ss / 128.f + EPS);

    const float c = cosb[(size_t)s * HD + lane];
    const float sn = sinb[(size_t)s * HD + lane];
    float o1 = x1 * rn * c - x2 * rn * sn;   // d = lane
    float o2 = x2 * rn * c + x1 * rn * sn;   // d = lane + 64
    if (is_q) { o1 *= QK_SCALE; o2 *= QK_SCALE; }

    const unsigned short h1 = f2bf(o1), l1 = f2bf(o1 - bf2f(h1));
    const unsigned short h2 = f2bf(o2), l2 = f2bf(o2 - bf2f(h2));
    if (is_q) {
      const size_t base = (size_t)s * 2048 + hh * HD + lane;
      qh[base] = h1; ql[base] = l1;
      qh[base + 64] = h2; ql[base + 64] = l2;
    } else {
      const size_t base = (size_t)s * 1024 + (hh - 16) * HD + lane;
      kh[base] = h1; kl[base] = l1;
      kh[base + 64] = h2; kl[base + 64] = l2;
    }
  }
}

// ---------------------------------------------------------------------------
// 64x64-tile plain bf16 MFMA GEMM (V proj: 512 blocks = 2/CU; wo proj:
// 1024 blocks = 4/CU). MODE 0: float C. MODE 1: transposed bf16 Ct[n][ldc]+m.
// ---------------------------------------------------------------------------
template <int MODE, typename OT>
__global__ __launch_bounds__(256) void gemm_bf16_6464(const unsigned short* __restrict__ A,
                                                      const unsigned short* __restrict__ Bt,
                                                      OT* __restrict__ C,
                                                      int M, int N, int K, int ldc) {
  __shared__ unsigned short As[64 * BK];
  __shared__ unsigned short Bs[64 * BK];

  const int tid = threadIdx.x;
  const int lane = tid & 63;
  const int wave = tid >> 6;
  const int m0 = blockIdx.y * 64;
  const int n0 = blockIdx.x * 64;

  const int qm = (wave >> 1) * 32;
  const int qn = (wave & 1) * 32;
  const int l15 = lane & 15;
  const int quad = lane >> 4;

  const int st_row = lane >> 2;
  const int st_col = (lane & 3) * 8;

  f32x4 acc[2][2] = {};

  for (int k0 = 0; k0 < K; k0 += BK) {
    {
      const int rb = wave * 16;
      gload16(A + (size_t)(m0 + rb + st_row) * K + k0 + st_col, &As[rb * BK]);
      gload16(Bt + (size_t)(n0 + rb + st_row) * K + k0 + st_col, &Bs[rb * BK]);
    }
    __syncthreads();

    s16x8 a[2], b[2];
#pragma unroll
    for (int i = 0; i < 2; ++i)
      a[i] = *(const s16x8*)&As[(qm + i * 16 + l15) * BK + quad * 8];
#pragma unroll
    for (int j = 0; j < 2; ++j)
      b[j] = *(const s16x8*)&Bs[(qn + j * 16 + l15) * BK + quad * 8];
#pragma unroll
    for (int i = 0; i < 2; ++i)
#pragma unroll
      for (int j = 0; j < 2; ++j)
        acc[i][j] = __builtin_amdgcn_mfma_f32_16x16x32_bf16(a[i], b[j], acc[i][j], 0, 0, 0);
    __syncthreads();
  }

#pragma unroll
  for (int i = 0; i < 2; ++i) {
    const int row_base = m0 + qm + i * 16 + quad * 4;
#pragma unroll
    for (int j = 0; j < 2; ++j) {
      const int col = n0 + qn + j * 16 + l15;
      if constexpr (MODE == 0) {
#pragma unroll
        for (int r = 0; r < 4; ++r)
          C[(size_t)(row_base + r) * ldc + col] = acc[i][j][r];
      } else {
        ushort4 u;
        u.x = f2bf(acc[i][j][0]); u.y = f2bf(acc[i][j][1]);
        u.z = f2bf(acc[i][j][2]); u.w = f2bf(acc[i][j][3]);
        *(ushort4*)((unsigned short*)C + (size_t)col * ldc + row_base) = u;
      }
    }
  }
}

// ---------------------------------------------------------------------------
// Flash attention, MFMA, single-buffer DMA + 2 blocks/CU (4 waves/SIMD).
// (Unchanged from round 3: 110 us, Occupancy 40%, MfmaUtil 26.)
// ---------------------------------------------------------------------------
#define FA_N 64
#define FA_NT (S / FA_N)

__global__ __launch_bounds__(512, 4) void attn_flash_mfma(const unsigned short* __restrict__ qh,
                                                          const unsigned short* __restrict__ ql,
                                                          const unsigned short* __restrict__ kh,
                                                          const unsigned short* __restrict__ kl,
                                                          const unsigned short* __restrict__ vt,
                                                          unsigned short* __restrict__ out) {
  const int h = blockIdx.y;
  const int kvh = h >> 1;
  const int m0 = blockIdx.x * 64;
  const int tid = threadIdx.x;
  const int lane = tid & 63;
  const int wave = tid >> 6;   // 0..7
  const int rg = wave >> 1;    // row group (16 q-rows)
  const int kg = wave & 1;     // key half (32 of 64 keys)
  const int l15 = lane & 15;
  const int quad = lane >> 4;

  __shared__ char smem[59392];
  unsigned short* Kh = (unsigned short*)(smem);            // [64][128] u16, 16KB
  unsigned short* Kl = (unsigned short*)(smem + 16384);
  unsigned short* Vt = (unsigned short*)(smem + 32768);    // [128 d][64 keys]
  unsigned short* Pt = (unsigned short*)(smem + 49152) + wave * 640;  // [16][40]

  // ---- DMA staging: each wave stages 8 K-rows (hi+lo) and 16 V-rows ----
  auto STAGE = [&](int nt) {
#pragma unroll
    for (int p = 0; p < 2; ++p) {
      const int kr = wave * 8 + p * 4 + (lane >> 4);
      const size_t ksrc = (size_t)(nt + kr) * 1024 + kvh * HD + ((lane & 15) ^ (kr & 15)) * 8;
      gload16(kh + ksrc, Kh + (wave * 8 + p * 4) * 128);
      gload16(kl + ksrc, Kl + (wave * 8 + p * 4) * 128);
      const int d = wave * 16 + p * 8 + (lane >> 3);
      const size_t vsrc = (size_t)(kvh * HD + d) * 2048 + nt + ((lane & 7) ^ (d & 7)) * 8;
      gload16(vt + vsrc, Vt + (wave * 16 + p * 8) * 64);
    }
  };

  // ---- Q fragments in registers (A-layout), once ----
  s16x8 qah[4], qal[4];
  {
    const int qrow = m0 + rg * 16 + l15;
#pragma unroll
    for (int ks = 0; ks < 4; ++ks) {
      const size_t off = (size_t)qrow * 2048 + h * HD + ks * 32 + quad * 8;
      qah[ks] = *(const s16x8*)(qh + off);
      qal[ks] = *(const s16x8*)(ql + off);
    }
  }

  f32x4 O[8] = {};
  float m_i[4], l_i[4];
#pragma unroll
  for (int r = 0; r < 4; ++r) { m_i[r] = -1e30f; l_i[r] = 0.f; }

  for (int t = 0; t < FA_NT; ++t) {
    __syncthreads();  // previous tile's fragment reads done
    STAGE(t * FA_N);
    __syncthreads();  // DMA drained (vmcnt 0) + visible to all waves

    // ---- S = Q K^T over this wave's 32-key half, split precision ----
    f32x4 sacc[2] = {};
    __builtin_amdgcn_s_setprio(1);
#pragma unroll
    for (int ks = 0; ks < 4; ++ks) {
      s16x8 bh[2], bl[2];
#pragma unroll
      for (int j = 0; j < 2; ++j) {
        const int row = kg * 32 + j * 16 + l15;
        const int ro = row * 128 + (((ks * 4 + quad) ^ l15) * 8);
        bh[j] = *(const s16x8*)&Kh[ro];
        bl[j] = *(const s16x8*)&Kl[ro];
      }
#pragma unroll
      for (int j = 0; j < 2; ++j) {
        sacc[j] = __builtin_amdgcn_mfma_f32_16x16x32_bf16(qah[ks], bh[j], sacc[j], 0, 0, 0);
        sacc[j] = __builtin_amdgcn_mfma_f32_16x16x32_bf16(qah[ks], bl[j], sacc[j], 0, 0, 0);
        sacc[j] = __builtin_amdgcn_mfma_f32_16x16x32_bf16(qal[ks], bh[j], sacc[j], 0, 0, 0);
      }
    }
    __builtin_amdgcn_s_setprio(0);

    // ---- online softmax; T13 defer-max; l stays per-lane-partial ----
    float mt[4];
    float dmax = -1e30f;
#pragma unroll
    for (int r = 0; r < 4; ++r) {
      float m = fmaxf(sacc[0][r], sacc[1][r]);
      m = fmaxf(m, __shfl_xor(m, 1));
      m = fmaxf(m, __shfl_xor(m, 2));
      m = fmaxf(m, __shfl_xor(m, 4));
      m = fmaxf(m, __shfl_xor(m, 8));
      mt[r] = m;
      dmax = fmaxf(dmax, m - m_i[r]);
    }
    if (__any(dmax > 8.f)) {   // wave-uniform rescale path
#pragma unroll
      for (int r = 0; r < 4; ++r) {
        const float mnew = fmaxf(m_i[r], mt[r]);
        const float alpha = __expf(m_i[r] - mnew);
        m_i[r] = mnew;
        l_i[r] *= alpha;
#pragma unroll
        for (int jd = 0; jd < 8; ++jd) O[jd][r] *= alpha;
      }
    }
#pragma unroll
    for (int r = 0; r < 4; ++r) {
      const float p0 = __expf(sacc[0][r] - m_i[r]);
      const float p1 = __expf(sacc[1][r] - m_i[r]);
      l_i[r] += p0 + p1;
      const int prow = quad * 4 + r;
      Pt[prow * 40 + l15] = f2bf(p0);
      Pt[prow * 40 + 16 + l15] = f2bf(p1);
    }
    // no barrier: Pt is per-wave private; DS ops within a wave are ordered.

    // ---- O += P V over this wave's 32 keys ----
    const s16x8 pa = *(const s16x8*)&Pt[l15 * 40 + quad * 8];
    __builtin_amdgcn_s_setprio(1);
#pragma unroll
    for (int jd = 0; jd < 8; ++jd) {
      const int d = jd * 16 + l15;
      const int cp = ((kg * 4 + quad) ^ (d & 7)) * 8;
      const s16x8 vb = *(const s16x8*)&Vt[d * 64 + cp];
      O[jd] = __builtin_amdgcn_mfma_f32_16x16x32_bf16(pa, vb, O[jd], 0, 0, 0);
    }
    __builtin_amdgcn_s_setprio(0);
  }

  // ---- deferred l reduction (once instead of per tile) ----
#pragma unroll
  for (int r = 0; r < 4; ++r) {
    float ls = l_i[r];
    ls += __shfl_xor(ls, 1);
    ls += __shfl_xor(ls, 2);
    ls += __shfl_xor(ls, 4);
    ls += __shfl_xor(ls, 8);
    l_i[r] = ls;
  }

  // ---- merge the two key-halves per row group, then store ----
  __syncthreads();  // all fragment reads done; reuse LDS
  float* Om = (float*)smem;                 // [64 rows][128]
  float* ms = (float*)(smem + 32768);       // [64]
  float* ls2 = (float*)(smem + 33024);      // [64]

  if (kg == 1) {
#pragma unroll
    for (int r = 0; r < 4; ++r) {
      const int row = rg * 16 + quad * 4 + r;
      if (l15 == 0) { ms[row] = m_i[r]; ls2[row] = l_i[r]; }
#pragma unroll
      for (int jd = 0; jd < 8; ++jd)
        Om[(size_t)row * 128 + jd * 16 + l15] = O[jd][r];
    }
  }
  __syncthreads();
  if (kg == 0) {
#pragma unroll
    for (int r = 0; r < 4; ++r) {
      const int row = rg * 16 + quad * 4 + r;
      const float mB = ms[row];
      const float lB = ls2[row];
      const float mS = fmaxf(m_i[r], mB);
      const float aA = __expf(m_i[r] - mS);
      const float aB = __expf(mB - mS);
      const float inv = 1.f / (aA * l_i[r] + aB * lB);
      const int grow = m0 + row;
#pragma unroll
      for (int jd = 0; jd < 8; ++jd) {
        const float oB = Om[(size_t)row * 128 + jd * 16 + l15];
        out[(size_t)grow * 2048 + h * HD + jd * 16 + l15] =
            f2bf((aA * O[jd][r] + aB * oB) * inv);
      }
    }
  }
}

// ---------------------------------------------------------------------------
extern "C" void kernel_launch(void* const* d_in, const int* in_sizes, int n_in,
                              void* d_out, int out_size, void* d_ws, size_t ws_size,
                              hipStream_t stream) {
  const float* hidden = (const float*)d_in[0];  // [S][HID]
  const float* cosb   = (const float*)d_in[1];  // [S][HD]
  const float* sinb   = (const float*)d_in[2];  // [S][HD]
  const float* wq     = (const float*)d_in[3];  // [HID][2048]
  const float* wk     = (const float*)d_in[4];  // [HID][1024]
  const float* wv     = (const float*)d_in[5];  // [HID][1024]
  const float* wo     = (const float*)d_in[6];  // [2048][HID]
  float* out = (float*)d_out;                   // [S][HID]

  // Workspace map (72 MB, regions reused once dead):
  char* w = (char*)d_ws;
  unsigned short* q_hi    = (unsigned short*)(w);                 //  0-8  [S][2048]
  unsigned short* q_lo    = (unsigned short*)(w + (8u << 20));    //  8-16
  unsigned short* k_hi    = (unsigned short*)(w + (16u << 20));   // 16-20 [S][1024]
  unsigned short* k_lo    = (unsigned short*)(w + (20u << 20));   // 20-24
  unsigned short* wqkT_hi = (unsigned short*)(w + (24u << 20));   // 24-36 (dead after QK gemm)
  unsigned short* wqkT_lo = (unsigned short*)(w + (36u << 20));   // 36-48 (dead after QK gemm)
  unsigned short* hid_hi  = (unsigned short*)(w + (48u << 20));   // 48-56 (dead after V gemm)
  unsigned short* hid_lo  = (unsigned short*)(w + (56u << 20));   // 56-64 (dead after QK gemm)
  unsigned short* vt_b    = (unsigned short*)(w + (64u << 20));   // 64-68 V^T bf16 [1024][2048]
  unsigned short* wvT     = (unsigned short*)(w + (68u << 20));   // 68-72
  // reuse after V gemm / QK gemm:
  unsigned short* woT     = (unsigned short*)(w + (48u << 20));   // 48-56 [2048][2048]
  unsigned short* a_b     = (unsigned short*)(w + (56u << 20));   // 56-64 [S][2048]

  dim3 blk(256);

  // prologue
  f32_to_bf16_split<<<dim3((S * HID / 4 + 255) / 256), blk, 0, stream>>>(hidden, hid_hi, hid_lo, S * HID / 4);
  transpose_to_bf16_split<<<dim3(32, 32), blk, 0, stream>>>(wq, wqkT_hi, wqkT_lo, HID, 2048);
  transpose_to_bf16_split<<<dim3(16, 32), blk, 0, stream>>>(wk, wqkT_hi + (size_t)2048 * 2048,
                                                            wqkT_lo + (size_t)2048 * 2048, HID, 1024);
  transpose_to_bf16<<<dim3(16, 32), blk, 0, stream>>>(wv, wvT, 2048, 1024);

  // Fused QK projection + RMSNorm + RoPE + split store -> q/k hi/lo directly.
  // 64x128 tile (one head per block-col), grid 24x32 = 768 = 3/CU even.
  gemm_qk_fused<<<dim3(24, 32), blk, 0, stream>>>(hid_hi, hid_lo, wqkT_hi, wqkT_lo,
                                                  cosb, sinb, q_hi, q_lo, k_hi, k_lo);

  // V projection -> transposed bf16 [1024][2048]; 64x64 tile, 512 blocks = 2/CU
  gemm_bf16_6464<1, unsigned short><<<dim3(1024 / 64, S / 64), blk, 0, stream>>>(
      hid_hi, wvT, vt_b, S, 1024, HID, 2048);

  // wo transpose into dead hid_hi region (after V gemm in stream order)
  transpose_to_bf16<<<dim3(32, 32), blk, 0, stream>>>(wo, woT, 2048, HID);

  // MFMA flash attention (512 thr, 2 blocks/CU, 4 waves/SIMD) -> bf16 [S][2048]
  attn_flash_mfma<<<dim3(S / 64, NH), dim3(512), 0, stream>>>(q_hi, q_lo, k_hi, k_lo, vt_b, a_b);

  // output projection -> fp32 out; 64x64 tile, 1024 blocks = 4/CU
  gemm_bf16_6464<0, float><<<dim3(HID / 64, S / 64), blk, 0, stream>>>(
      a_b, woT, out, S, HID, 2048, HID);
}

// Round 6
// 367.088 us; speedup vs baseline: 1.0530x; 1.0530x over previous
//
#include <hip/hip_runtime.h>
#include <hip/hip_bf16.h>
#include <math.h>

// Problem constants
#define S 2048
#define HID 2048
#define NH 16
#define KVH 8
#define HD 128
#define EPS 1e-6f
#define QK_SCALE 11.313708498984760390f  // 1/SCALING = sqrt(128)

typedef __attribute__((ext_vector_type(8))) short s16x8;
typedef __attribute__((ext_vector_type(4))) float f32x4;

__device__ __forceinline__ unsigned short f2bf(float f) {
  __hip_bfloat16 h = __float2bfloat16(f);
  return *(unsigned short*)&h;
}
__device__ __forceinline__ float bf2f(unsigned short u) {
  unsigned int x = ((unsigned int)u) << 16;
  return __builtin_bit_cast(float, x);
}

__device__ __forceinline__ void gload16(const void* g, void* l) {
  __builtin_amdgcn_global_load_lds(
      (const __attribute__((address_space(1))) void*)g,
      (__attribute__((address_space(3))) void*)l, 16, 0, 0);
}

// ---------------------------------------------------------------------------
// fp32 -> split bf16 (hi + lo) elementwise.
// ---------------------------------------------------------------------------
__global__ __launch_bounds__(256) void f32_to_bf16_split(const float* __restrict__ in,
                                                         unsigned short* __restrict__ hi,
                                                         unsigned short* __restrict__ lo,
                                                         int n4) {
  const int i = blockIdx.x * 256 + threadIdx.x;
  if (i < n4) {
    const float4 v = *(const float4*)(in + (size_t)i * 4);
    ushort4 h, l;
    h.x = f2bf(v.x); l.x = f2bf(v.x - bf2f(h.x));
    h.y = f2bf(v.y); l.y = f2bf(v.y - bf2f(h.y));
    h.z = f2bf(v.z); l.z = f2bf(v.z - bf2f(h.z));
    h.w = f2bf(v.w); l.w = f2bf(v.w - bf2f(h.w));
    *(ushort4*)(hi + (size_t)i * 4) = h;
    *(ushort4*)(lo + (size_t)i * 4) = l;
  }
}

// ---------------------------------------------------------------------------
// Transpose fp32 [K][N] -> bf16 [N][K], plain.
// ---------------------------------------------------------------------------
__global__ __launch_bounds__(256) void transpose_to_bf16(const float* __restrict__ in,
                                                         unsigned short* __restrict__ out,
                                                         int K, int N) {
  __shared__ float t[64][65];
  const int n0 = blockIdx.x * 64;
  const int k0 = blockIdx.y * 64;
  const int tid = threadIdx.x;

  for (int idx = tid; idx < 64 * 16; idx += 256) {
    const int r = idx >> 4;
    const int c4 = (idx & 15) * 4;
    const float4 v = *(const float4*)(in + (size_t)(k0 + r) * N + n0 + c4);
    t[r][c4 + 0] = v.x; t[r][c4 + 1] = v.y; t[r][c4 + 2] = v.z; t[r][c4 + 3] = v.w;
  }
  __syncthreads();
  for (int idx = tid; idx < 64 * 16; idx += 256) {
    const int a = idx >> 4;
    const int b4 = (idx & 15) * 4;
    ushort4 u;
    u.x = f2bf(t[b4 + 0][a]); u.y = f2bf(t[b4 + 1][a]);
    u.z = f2bf(t[b4 + 2][a]); u.w = f2bf(t[b4 + 3][a]);
    *(ushort4*)(out + (size_t)(n0 + a) * K + k0 + b4) = u;
  }
}

// ---------------------------------------------------------------------------
// Transpose fp32 [K][N] -> split bf16 hi/lo [N][K].
// ---------------------------------------------------------------------------
__global__ __launch_bounds__(256) void transpose_to_bf16_split(const float* __restrict__ in,
                                                               unsigned short* __restrict__ ohi,
                                                               unsigned short* __restrict__ olo,
                                                               int K, int N) {
  __shared__ float t[64][65];
  const int n0 = blockIdx.x * 64;
  const int k0 = blockIdx.y * 64;
  const int tid = threadIdx.x;

  for (int idx = tid; idx < 64 * 16; idx += 256) {
    const int r = idx >> 4;
    const int c4 = (idx & 15) * 4;
    const float4 v = *(const float4*)(in + (size_t)(k0 + r) * N + n0 + c4);
    t[r][c4 + 0] = v.x; t[r][c4 + 1] = v.y; t[r][c4 + 2] = v.z; t[r][c4 + 3] = v.w;
  }
  __syncthreads();
  for (int idx = tid; idx < 64 * 16; idx += 256) {
    const int a = idx >> 4;
    const int b4 = (idx & 15) * 4;
    ushort4 h, l;
#pragma unroll
    for (int q = 0; q < 4; ++q) {
      const float v = t[b4 + q][a];
      const unsigned short hu = f2bf(v);
      const unsigned short lu = f2bf(v - bf2f(hu));
      ((unsigned short*)&h)[q] = hu;
      ((unsigned short*)&l)[q] = lu;
    }
    *(ushort4*)(ohi + (size_t)(n0 + a) * K + k0 + b4) = h;
    *(ushort4*)(olo + (size_t)(n0 + a) * K + k0 + b4) = l;
  }
}

// ===========================================================================
// Round 6 GEMM core: BK=64 (128B LDS rows) + XOR swizzle chunk^=(row&7).
// Staging keeps gload_lds LINEAR dst (lane l -> base + l*16 == row-major
// [8 rows][8 chunks]); the swizzle is pre-applied to the per-lane GLOBAL
// source column (rule: both-sides-or-neither). Fragment reads use
// pos = (ks*4+quad) ^ (row&7): 8 consecutive rows hit 8 distinct 16B slots
// -> conflict-free ds_read_b128 (was 8-way at BK=32 / 64B rows).
// ===========================================================================
#define BK 64

// ---------------------------------------------------------------------------
// FUSED QK projection: 64x128-tile split-precision GEMM + RMSNorm + RoPE +
// split-bf16 store. One block column == one head. Grid 24x32 = 768 = 3/CU.
// ---------------------------------------------------------------------------
__global__ __launch_bounds__(256) void gemm_qk_fused(const unsigned short* __restrict__ Ahi,
                                                     const unsigned short* __restrict__ Alo,
                                                     const unsigned short* __restrict__ Bhi,
                                                     const unsigned short* __restrict__ Blo,
                                                     const float* __restrict__ cosb,
                                                     const float* __restrict__ sinb,
                                                     unsigned short* __restrict__ qh,
                                                     unsigned short* __restrict__ ql,
                                                     unsigned short* __restrict__ kh,
                                                     unsigned short* __restrict__ kl) {
  __shared__ char smem[49152];
  unsigned short* AsH = (unsigned short*)smem;             // [64][64] 8KB
  unsigned short* AsL = (unsigned short*)(smem + 8192);
  unsigned short* BsH = (unsigned short*)(smem + 16384);   // [128][64] 16KB
  unsigned short* BsL = (unsigned short*)(smem + 32768);
  float* Sf = (float*)smem;  // [64][132] fp32 after the K-loop (33792B)

  const int tid = threadIdx.x;
  const int lane = tid & 63;
  const int wave = tid >> 6;
  const int hh = blockIdx.x;          // head 0..23 (q:0-15, k:16-23)
  const int m0 = blockIdx.y * 64;
  const int n0 = hh * 128;

  const int qm = (wave >> 1) * 32;
  const int qn = (wave & 1) * 64;
  const int l15 = lane & 15;
  const int quad = lane >> 4;

  // staging geometry: lane covers row st_row (of 8), chunk st_ch (8 elems)
  const int st_row = lane >> 3;            // 0..7
  const int st_ch = lane & 7;              // 0..7
  const int st_col = ((st_ch ^ st_row) * 8);  // pre-swizzled global column

  f32x4 acc[2][4] = {};

  for (int k0 = 0; k0 < HID; k0 += BK) {
    // A: wave w stages rows w*16 .. w*16+15 (hi+lo), 8 rows per gload16
#pragma unroll
    for (int p = 0; p < 2; ++p) {
      const int rb = wave * 16 + p * 8;
      const size_t aoff = (size_t)(m0 + rb + st_row) * HID + k0 + st_col;
      gload16(Ahi + aoff, &AsH[rb * BK]);
      gload16(Alo + aoff, &AsL[rb * BK]);
    }
    // B: wave w stages rows w*32 .. w*32+31 (hi+lo)
#pragma unroll
    for (int p = 0; p < 4; ++p) {
      const int rb = wave * 32 + p * 8;
      const size_t boff = (size_t)(n0 + rb + st_row) * HID + k0 + st_col;
      gload16(Bhi + boff, &BsH[rb * BK]);
      gload16(Blo + boff, &BsL[rb * BK]);
    }
    __syncthreads();

#pragma unroll
    for (int ks = 0; ks < 2; ++ks) {
      s16x8 ah[2], al[2], bh[4], bl[4];
#pragma unroll
      for (int i = 0; i < 2; ++i) {
        const int row = qm + i * 16 + l15;
        const int ro = row * BK + (((ks * 4 + quad) ^ (row & 7)) * 8);
        ah[i] = *(const s16x8*)&AsH[ro];
        al[i] = *(const s16x8*)&AsL[ro];
      }
#pragma unroll
      for (int j = 0; j < 4; ++j) {
        const int row = qn + j * 16 + l15;
        const int ro = row * BK + (((ks * 4 + quad) ^ (row & 7)) * 8);
        bh[j] = *(const s16x8*)&BsH[ro];
        bl[j] = *(const s16x8*)&BsL[ro];
      }
#pragma unroll
      for (int i = 0; i < 2; ++i)
#pragma unroll
        for (int j = 0; j < 4; ++j) {
          acc[i][j] = __builtin_amdgcn_mfma_f32_16x16x32_bf16(ah[i], bh[j], acc[i][j], 0, 0, 0);
          acc[i][j] = __builtin_amdgcn_mfma_f32_16x16x32_bf16(ah[i], bl[j], acc[i][j], 0, 0, 0);
          acc[i][j] = __builtin_amdgcn_mfma_f32_16x16x32_bf16(al[i], bh[j], acc[i][j], 0, 0, 0);
        }
    }
    __syncthreads();
  }

  // ---- epilogue: S -> LDS (fp32, padded row stride 132) ----
#pragma unroll
  for (int i = 0; i < 2; ++i) {
    const int rbase = qm + i * 16 + quad * 4;
#pragma unroll
    for (int j = 0; j < 4; ++j) {
      const int col = qn + j * 16 + l15;
#pragma unroll
      for (int r = 0; r < 4; ++r)
        Sf[(rbase + r) * 132 + col] = acc[i][j][r];
    }
  }
  __syncthreads();

  // ---- fused RMSNorm + RoPE + split store; wave owns rows wave*16..+15 ----
  const bool is_q = (hh < 16);
  for (int rr = 0; rr < 16; ++rr) {
    const int row = wave * 16 + rr;
    const int s = m0 + row;
    const float x1 = Sf[row * 132 + lane];
    const float x2 = Sf[row * 132 + 64 + lane];

    float ss = x1 * x1 + x2 * x2;
    ss += __shfl_xor(ss, 1);
    ss += __shfl_xor(ss, 2);
    ss += __shfl_xor(ss, 4);
    ss += __shfl_xor(ss, 8);
    ss += __shfl_xor(ss, 16);
    ss += __shfl_xor(ss, 32);
    const float rn = rsqrtf(ss / 128.f + EPS);

    const float c = cosb[(size_t)s * HD + lane];
    const float sn = sinb[(size_t)s * HD + lane];
    float o1 = x1 * rn * c - x2 * rn * sn;   // d = lane
    float o2 = x2 * rn * c + x1 * rn * sn;   // d = lane + 64
    if (is_q) { o1 *= QK_SCALE; o2 *= QK_SCALE; }

    const unsigned short h1 = f2bf(o1), l1 = f2bf(o1 - bf2f(h1));
    const unsigned short h2 = f2bf(o2), l2 = f2bf(o2 - bf2f(h2));
    if (is_q) {
      const size_t base = (size_t)s * 2048 + hh * HD + lane;
      qh[base] = h1; ql[base] = l1;
      qh[base + 64] = h2; ql[base + 64] = l2;
    } else {
      const size_t base = (size_t)s * 1024 + (hh - 16) * HD + lane;
      kh[base] = h1; kl[base] = l1;
      kh[base + 64] = h2; kl[base + 64] = l2;
    }
  }
}

// ---------------------------------------------------------------------------
// 64x64-tile plain bf16 MFMA GEMM, BK=64 + swizzle (V proj: 512 blocks =
// 2/CU; wo proj: 1024 = 4/CU). MODE 0: float C. MODE 1: transposed bf16.
// ---------------------------------------------------------------------------
template <int MODE, typename OT>
__global__ __launch_bounds__(256) void gemm_bf16_6464(const unsigned short* __restrict__ A,
                                                      const unsigned short* __restrict__ Bt,
                                                      OT* __restrict__ C,
                                                      int M, int N, int K, int ldc) {
  __shared__ unsigned short As[64 * BK];   // 8KB
  __shared__ unsigned short Bs[64 * BK];   // 8KB

  const int tid = threadIdx.x;
  const int lane = tid & 63;
  const int wave = tid >> 6;
  const int m0 = blockIdx.y * 64;
  const int n0 = blockIdx.x * 64;

  const int qm = (wave >> 1) * 32;
  const int qn = (wave & 1) * 32;
  const int l15 = lane & 15;
  const int quad = lane >> 4;

  const int st_row = lane >> 3;
  const int st_col = (((lane & 7) ^ st_row) * 8);

  f32x4 acc[2][2] = {};

  for (int k0 = 0; k0 < K; k0 += BK) {
#pragma unroll
    for (int p = 0; p < 2; ++p) {
      const int rb = wave * 16 + p * 8;
      gload16(A + (size_t)(m0 + rb + st_row) * K + k0 + st_col, &As[rb * BK]);
      gload16(Bt + (size_t)(n0 + rb + st_row) * K + k0 + st_col, &Bs[rb * BK]);
    }
    __syncthreads();

#pragma unroll
    for (int ks = 0; ks < 2; ++ks) {
      s16x8 a[2], b[2];
#pragma unroll
      for (int i = 0; i < 2; ++i) {
        const int row = qm + i * 16 + l15;
        a[i] = *(const s16x8*)&As[row * BK + (((ks * 4 + quad) ^ (row & 7)) * 8)];
      }
#pragma unroll
      for (int j = 0; j < 2; ++j) {
        const int row = qn + j * 16 + l15;
        b[j] = *(const s16x8*)&Bs[row * BK + (((ks * 4 + quad) ^ (row & 7)) * 8)];
      }
#pragma unroll
      for (int i = 0; i < 2; ++i)
#pragma unroll
        for (int j = 0; j < 2; ++j)
          acc[i][j] = __builtin_amdgcn_mfma_f32_16x16x32_bf16(a[i], b[j], acc[i][j], 0, 0, 0);
    }
    __syncthreads();
  }

#pragma unroll
  for (int i = 0; i < 2; ++i) {
    const int row_base = m0 + qm + i * 16 + quad * 4;
#pragma unroll
    for (int j = 0; j < 2; ++j) {
      const int col = n0 + qn + j * 16 + l15;
      if constexpr (MODE == 0) {
#pragma unroll
        for (int r = 0; r < 4; ++r)
          C[(size_t)(row_base + r) * ldc + col] = acc[i][j][r];
      } else {
        ushort4 u;
        u.x = f2bf(acc[i][j][0]); u.y = f2bf(acc[i][j][1]);
        u.z = f2bf(acc[i][j][2]); u.w = f2bf(acc[i][j][3]);
        *(ushort4*)((unsigned short*)C + (size_t)col * ldc + row_base) = u;
      }
    }
  }
}

// ---------------------------------------------------------------------------
// Flash attention, MFMA, single-buffer DMA + 2 blocks/CU (4 waves/SIMD).
// (Unchanged from round 3: 110 us, Occupancy 40%, MfmaUtil 26. Control.)
// ---------------------------------------------------------------------------
#define FA_N 64
#define FA_NT (S / FA_N)

__global__ __launch_bounds__(512, 4) void attn_flash_mfma(const unsigned short* __restrict__ qh,
                                                          const unsigned short* __restrict__ ql,
                                                          const unsigned short* __restrict__ kh,
                                                          const unsigned short* __restrict__ kl,
                                                          const unsigned short* __restrict__ vt,
                                                          unsigned short* __restrict__ out) {
  const int h = blockIdx.y;
  const int kvh = h >> 1;
  const int m0 = blockIdx.x * 64;
  const int tid = threadIdx.x;
  const int lane = tid & 63;
  const int wave = tid >> 6;   // 0..7
  const int rg = wave >> 1;    // row group (16 q-rows)
  const int kg = wave & 1;     // key half (32 of 64 keys)
  const int l15 = lane & 15;
  const int quad = lane >> 4;

  __shared__ char smem[59392];
  unsigned short* Kh = (unsigned short*)(smem);            // [64][128] u16, 16KB
  unsigned short* Kl = (unsigned short*)(smem + 16384);
  unsigned short* Vt = (unsigned short*)(smem + 32768);    // [128 d][64 keys]
  unsigned short* Pt = (unsigned short*)(smem + 49152) + wave * 640;  // [16][40]

  // ---- DMA staging: each wave stages 8 K-rows (hi+lo) and 16 V-rows ----
  auto STAGE = [&](int nt) {
#pragma unroll
    for (int p = 0; p < 2; ++p) {
      const int kr = wave * 8 + p * 4 + (lane >> 4);
      const size_t ksrc = (size_t)(nt + kr) * 1024 + kvh * HD + ((lane & 15) ^ (kr & 15)) * 8;
      gload16(kh + ksrc, Kh + (wave * 8 + p * 4) * 128);
      gload16(kl + ksrc, Kl + (wave * 8 + p * 4) * 128);
      const int d = wave * 16 + p * 8 + (lane >> 3);
      const size_t vsrc = (size_t)(kvh * HD + d) * 2048 + nt + ((lane & 7) ^ (d & 7)) * 8;
      gload16(vt + vsrc, Vt + (wave * 16 + p * 8) * 64);
    }
  };

  // ---- Q fragments in registers (A-layout), once ----
  s16x8 qah[4], qal[4];
  {
    const int qrow = m0 + rg * 16 + l15;
#pragma unroll
    for (int ks = 0; ks < 4; ++ks) {
      const size_t off = (size_t)qrow * 2048 + h * HD + ks * 32 + quad * 8;
      qah[ks] = *(const s16x8*)(qh + off);
      qal[ks] = *(const s16x8*)(ql + off);
    }
  }

  f32x4 O[8] = {};
  float m_i[4], l_i[4];
#pragma unroll
  for (int r = 0; r < 4; ++r) { m_i[r] = -1e30f; l_i[r] = 0.f; }

  for (int t = 0; t < FA_NT; ++t) {
    __syncthreads();  // previous tile's fragment reads done
    STAGE(t * FA_N);
    __syncthreads();  // DMA drained (vmcnt 0) + visible to all waves

    // ---- S = Q K^T over this wave's 32-key half, split precision ----
    f32x4 sacc[2] = {};
    __builtin_amdgcn_s_setprio(1);
#pragma unroll
    for (int ks = 0; ks < 4; ++ks) {
      s16x8 bh[2], bl[2];
#pragma unroll
      for (int j = 0; j < 2; ++j) {
        const int row = kg * 32 + j * 16 + l15;
        const int ro = row * 128 + (((ks * 4 + quad) ^ l15) * 8);
        bh[j] = *(const s16x8*)&Kh[ro];
        bl[j] = *(const s16x8*)&Kl[ro];
      }
#pragma unroll
      for (int j = 0; j < 2; ++j) {
        sacc[j] = __builtin_amdgcn_mfma_f32_16x16x32_bf16(qah[ks], bh[j], sacc[j], 0, 0, 0);
        sacc[j] = __builtin_amdgcn_mfma_f32_16x16x32_bf16(qah[ks], bl[j], sacc[j], 0, 0, 0);
        sacc[j] = __builtin_amdgcn_mfma_f32_16x16x32_bf16(qal[ks], bh[j], sacc[j], 0, 0, 0);
      }
    }
    __builtin_amdgcn_s_setprio(0);

    // ---- online softmax; T13 defer-max; l stays per-lane-partial ----
    float mt[4];
    float dmax = -1e30f;
#pragma unroll
    for (int r = 0; r < 4; ++r) {
      float m = fmaxf(sacc[0][r], sacc[1][r]);
      m = fmaxf(m, __shfl_xor(m, 1));
      m = fmaxf(m, __shfl_xor(m, 2));
      m = fmaxf(m, __shfl_xor(m, 4));
      m = fmaxf(m, __shfl_xor(m, 8));
      mt[r] = m;
      dmax = fmaxf(dmax, m - m_i[r]);
    }
    if (__any(dmax > 8.f)) {   // wave-uniform rescale path
#pragma unroll
      for (int r = 0; r < 4; ++r) {
        const float mnew = fmaxf(m_i[r], mt[r]);
        const float alpha = __expf(m_i[r] - mnew);
        m_i[r] = mnew;
        l_i[r] *= alpha;
#pragma unroll
        for (int jd = 0; jd < 8; ++jd) O[jd][r] *= alpha;
      }
    }
#pragma unroll
    for (int r = 0; r < 4; ++r) {
      const float p0 = __expf(sacc[0][r] - m_i[r]);
      const float p1 = __expf(sacc[1][r] - m_i[r]);
      l_i[r] += p0 + p1;
      const int prow = quad * 4 + r;
      Pt[prow * 40 + l15] = f2bf(p0);
      Pt[prow * 40 + 16 + l15] = f2bf(p1);
    }
    // no barrier: Pt is per-wave private; DS ops within a wave are ordered.

    // ---- O += P V over this wave's 32 keys ----
    const s16x8 pa = *(const s16x8*)&Pt[l15 * 40 + quad * 8];
    __builtin_amdgcn_s_setprio(1);
#pragma unroll
    for (int jd = 0; jd < 8; ++jd) {
      const int d = jd * 16 + l15;
      const int cp = ((kg * 4 + quad) ^ (d & 7)) * 8;
      const s16x8 vb = *(const s16x8*)&Vt[d * 64 + cp];
      O[jd] = __builtin_amdgcn_mfma_f32_16x16x32_bf16(pa, vb, O[jd], 0, 0, 0);
    }
    __builtin_amdgcn_s_setprio(0);
  }

  // ---- deferred l reduction (once instead of per tile) ----
#pragma unroll
  for (int r = 0; r < 4; ++r) {
    float ls = l_i[r];
    ls += __shfl_xor(ls, 1);
    ls += __shfl_xor(ls, 2);
    ls += __shfl_xor(ls, 4);
    ls += __shfl_xor(ls, 8);
    l_i[r] = ls;
  }

  // ---- merge the two key-halves per row group, then store ----
  __syncthreads();  // all fragment reads done; reuse LDS
  float* Om = (float*)smem;                 // [64 rows][128]
  float* ms = (float*)(smem + 32768);       // [64]
  float* ls2 = (float*)(smem + 33024);      // [64]

  if (kg == 1) {
#pragma unroll
    for (int r = 0; r < 4; ++r) {
      const int row = rg * 16 + quad * 4 + r;
      if (l15 == 0) { ms[row] = m_i[r]; ls2[row] = l_i[r]; }
#pragma unroll
      for (int jd = 0; jd < 8; ++jd)
        Om[(size_t)row * 128 + jd * 16 + l15] = O[jd][r];
    }
  }
  __syncthreads();
  if (kg == 0) {
#pragma unroll
    for (int r = 0; r < 4; ++r) {
      const int row = rg * 16 + quad * 4 + r;
      const float mB = ms[row];
      const float lB = ls2[row];
      const float mS = fmaxf(m_i[r], mB);
      const float aA = __expf(m_i[r] - mS);
      const float aB = __expf(mB - mS);
      const float inv = 1.f / (aA * l_i[r] + aB * lB);
      const int grow = m0 + row;
#pragma unroll
      for (int jd = 0; jd < 8; ++jd) {
        const float oB = Om[(size_t)row * 128 + jd * 16 + l15];
        out[(size_t)grow * 2048 + h * HD + jd * 16 + l15] =
            f2bf((aA * O[jd][r] + aB * oB) * inv);
      }
    }
  }
}

// ---------------------------------------------------------------------------
extern "C" void kernel_launch(void* const* d_in, const int* in_sizes, int n_in,
                              void* d_out, int out_size, void* d_ws, size_t ws_size,
                              hipStream_t stream) {
  const float* hidden = (const float*)d_in[0];  // [S][HID]
  const float* cosb   = (const float*)d_in[1];  // [S][HD]
  const float* sinb   = (const float*)d_in[2];  // [S][HD]
  const float* wq     = (const float*)d_in[3];  // [HID][2048]
  const float* wk     = (const float*)d_in[4];  // [HID][1024]
  const float* wv     = (const float*)d_in[5];  // [HID][1024]
  const float* wo     = (const float*)d_in[6];  // [2048][HID]
  float* out = (float*)d_out;                   // [S][HID]

  // Workspace map (72 MB, regions reused once dead):
  char* w = (char*)d_ws;
  unsigned short* q_hi    = (unsigned short*)(w);                 //  0-8  [S][2048]
  unsigned short* q_lo    = (unsigned short*)(w + (8u << 20));    //  8-16
  unsigned short* k_hi    = (unsigned short*)(w + (16u << 20));   // 16-20 [S][1024]
  unsigned short* k_lo    = (unsigned short*)(w + (20u << 20));   // 20-24
  unsigned short* wqkT_hi = (unsigned short*)(w + (24u << 20));   // 24-36 (dead after QK gemm)
  unsigned short* wqkT_lo = (unsigned short*)(w + (36u << 20));   // 36-48 (dead after QK gemm)
  unsigned short* hid_hi  = (unsigned short*)(w + (48u << 20));   // 48-56 (dead after V gemm)
  unsigned short* hid_lo  = (unsigned short*)(w + (56u << 20));   // 56-64 (dead after QK gemm)
  unsigned short* vt_b    = (unsigned short*)(w + (64u << 20));   // 64-68 V^T bf16 [1024][2048]
  unsigned short* wvT     = (unsigned short*)(w + (68u << 20));   // 68-72
  // reuse after V gemm / QK gemm:
  unsigned short* woT     = (unsigned short*)(w + (48u << 20));   // 48-56 [2048][2048]
  unsigned short* a_b     = (unsigned short*)(w + (56u << 20));   // 56-64 [S][2048]

  dim3 blk(256);

  // prologue
  f32_to_bf16_split<<<dim3((S * HID / 4 + 255) / 256), blk, 0, stream>>>(hidden, hid_hi, hid_lo, S * HID / 4);
  transpose_to_bf16_split<<<dim3(32, 32), blk, 0, stream>>>(wq, wqkT_hi, wqkT_lo, HID, 2048);
  transpose_to_bf16_split<<<dim3(16, 32), blk, 0, stream>>>(wk, wqkT_hi + (size_t)2048 * 2048,
                                                            wqkT_lo + (size_t)2048 * 2048, HID, 1024);
  transpose_to_bf16<<<dim3(16, 32), blk, 0, stream>>>(wv, wvT, 2048, 1024);

  // Fused QK projection + RMSNorm + RoPE + split store -> q/k hi/lo directly.
  // 64x128 tile (one head per block-col), BK=64 swizzled, grid 24x32 = 768.
  gemm_qk_fused<<<dim3(24, 32), blk, 0, stream>>>(hid_hi, hid_lo, wqkT_hi, wqkT_lo,
                                                  cosb, sinb, q_hi, q_lo, k_hi, k_lo);

  // V projection -> transposed bf16 [1024][2048]; 64x64 tile, 512 blocks = 2/CU
  gemm_bf16_6464<1, unsigned short><<<dim3(1024 / 64, S / 64), blk, 0, stream>>>(
      hid_hi, wvT, vt_b, S, 1024, HID, 2048);

  // wo transpose into dead hid_hi region (after V gemm in stream order)
  transpose_to_bf16<<<dim3(32, 32), blk, 0, stream>>>(wo, woT, 2048, HID);

  // MFMA flash attention (512 thr, 2 blocks/CU, 4 waves/SIMD) -> bf16 [S][2048]
  attn_flash_mfma<<<dim3(S / 64, NH), dim3(512), 0, stream>>>(q_hi, q_lo, k_hi, k_lo, vt_b, a_b);

  // output projection -> fp32 out; 64x64 tile, 1024 blocks = 4/CU
  gemm_bf16_6464<0, float><<<dim3(HID / 64, S / 64), blk, 0, stream>>>(
      a_b, woT, out, S, HID, 2048, HID);
}